// Round 9
// baseline (314.384 us; speedup 1.0000x reference)
//
#include <hip/hip_runtime.h>
#include <hip/hip_bf16.h>

#define HH 448
#define WW 608
#define CC 128
#define HWP (HH*WW)
#define G 8   // experts per K2 block (4 waves x 2 rounds)

typedef __attribute__((ext_vector_type(8))) short bf16x8;
typedef __attribute__((ext_vector_type(4))) float f32x4;

__device__ __forceinline__ ushort f2b(float f) {
    __hip_bfloat16 b = __float2bfloat16(f);
    return *reinterpret_cast<ushort*>(&b);
}
__device__ __forceinline__ float b2f(ushort u) {
    union { unsigned v; float f; } x; x.v = ((unsigned)u) << 16; return x.f;
}
__device__ __forceinline__ float lrelu(float a) { return a > 0.f ? a : 0.01f * a; }

// Wcs swizzle (fallback K1 only)
__device__ __forceinline__ int swzA(int m, int k) {
    return m * 128 + ((((k >> 3) ^ (m & 15)) & 15) << 3) + (k & 7);
}
// Xs swizzle: [n][k], k<64. group = (k>>3) ^ (n&7) ^ ((n>>3)&7)
__device__ __forceinline__ int swzB(int n, int k) {
    return n * 64 + ((((k >> 3) ^ (n & 7) ^ ((n >> 3) & 7)) & 7) << 3) + (k & 7);
}

// ---------------- Kernel T: Wc fp32 -> bf16 in A-fragment lane layout ----------------
// WcF element ((h*4+s)*8+mt)*512 + l*8 + j  =  bf16(Wc[h][mt*16+(l&15)][s*32+(l>>4)*8+j])
// 917504 8-elem tasks = 3584 blocks x 256.
__global__ __launch_bounds__(256) void t_wcf(const float* __restrict__ Wc,
                                             ushort* __restrict__ WcF)
{
    const int gid = blockIdx.x * 256 + threadIdx.x;
    const int l  = gid & 63;
    const int mt = (gid >> 6) & 7;
    const int s  = (gid >> 9) & 3;
    const int h  = gid >> 11;
    const int m  = mt * 16 + (l & 15);
    const int k0 = s * 32 + (l >> 4) * 8;
    const float* src = Wc + ((size_t)(h * CC + m)) * 128 + k0;
    float4 v0 = *reinterpret_cast<const float4*>(src);
    float4 v1 = *reinterpret_cast<const float4*>(src + 4);
    bf16x8 r;
    r[0] = (short)f2b(v0.x); r[1] = (short)f2b(v0.y);
    r[2] = (short)f2b(v0.z); r[3] = (short)f2b(v0.w);
    r[4] = (short)f2b(v1.x); r[5] = (short)f2b(v1.y);
    r[6] = (short)f2b(v1.z); r[7] = (short)f2b(v1.w);
    *reinterpret_cast<bf16x8*>(WcF + (size_t)gid * 8) = r;
}

// ---------------- Kernel 1 (fast): classifier with direct-global A-frags ----------------
// grid (5, 448), block 512. No Wc LDS stage; A-frags stream from WcF (L3-resident).
__global__ __launch_bounds__(512, 4) void k1_fast(
    const float* __restrict__ x, const float* __restrict__ x_gt,
    const ushort* __restrict__ WcF, const float* __restrict__ bc,
    float* __restrict__ loss_out, int* __restrict__ labels,
    ushort* __restrict__ xT)
{
    __shared__ ushort Xs[128 * 64];
    __shared__ float bcs[128];

    const int h  = blockIdx.y;
    const int w0 = blockIdx.x * 128;
    const int t  = threadIdx.x;
    const int wv = t >> 6, l = t & 63;
    const int q  = l >> 4, lm = l & 15;
    const int nvalid = (WW - w0 < 128) ? (WW - w0) : 128;

    if (t < 128) bcs[t] = bc[h * CC + t];

    const ushort* WcFh = WcF + (size_t)h * (4 * 8 * 512);

    f32x4 acc[8];
    #pragma unroll
    for (int mt = 0; mt < 8; ++mt) acc[mt] = (f32x4){0.f, 0.f, 0.f, 0.f};

    for (int kh = 0; kh < 2; ++kh) {
        if (kh) __syncthreads();   // protect Xs from previous readers
        // stage x rows [kh*64, kh*64+64), cols [w0, w0+128) -> bf16 swizzled
        #pragma unroll
        for (int it = 0; it < 2; ++it) {
            int p = t + (it << 9);
            int i2 = p >> 5;
            int w = (p & 31) << 2;
            float4 v0, v1;
            if (w0 + w < WW) {
                const float* xb = x + ((size_t)(kh * 64 + i2 * 2)) * HWP + (size_t)h * WW + w0 + w;
                v0 = *reinterpret_cast<const float4*>(xb);
                v1 = *reinterpret_cast<const float4*>(xb + HWP);
            } else { v0 = make_float4(0, 0, 0, 0); v1 = v0; }
            int il = i2 << 1;
            *reinterpret_cast<ushort2*>(&Xs[swzB(w + 0, il)]) = make_ushort2(f2b(v0.x), f2b(v1.x));
            *reinterpret_cast<ushort2*>(&Xs[swzB(w + 1, il)]) = make_ushort2(f2b(v0.y), f2b(v1.y));
            *reinterpret_cast<ushort2*>(&Xs[swzB(w + 2, il)]) = make_ushort2(f2b(v0.z), f2b(v1.z));
            *reinterpret_cast<ushort2*>(&Xs[swzB(w + 3, il)]) = make_ushort2(f2b(v0.w), f2b(v1.w));
        }
        __syncthreads();

        #pragma unroll
        for (int kk = 0; kk < 2; ++kk) {
            const int kb = (kk << 5) + (q << 3);
            const int s  = kh * 2 + kk;
            bf16x8 bfrag = *reinterpret_cast<const bf16x8*>(&Xs[swzB((wv << 4) + lm, kb)]);
            #pragma unroll
            for (int mt = 0; mt < 8; ++mt) {
                bf16x8 afrag = *reinterpret_cast<const bf16x8*>(
                    WcFh + (((s << 3) + mt) << 9) + (l << 3));
                acc[mt] = __builtin_amdgcn_mfma_f32_16x16x32_bf16(afrag, bfrag, acc[mt], 0, 0, 0);
            }
        }

        // write xT (bf16) for this K-half
        #pragma unroll
        for (int it = 0; it < 2; ++it) {
            int g = t + (it << 9);
            int n = g >> 3, i8 = g & 7;
            if (n < nvalid) {
                bf16x8 v = *reinterpret_cast<const bf16x8*>(&Xs[swzB(n, i8 << 3)]);
                *reinterpret_cast<bf16x8*>(xT + ((size_t)(h * WW + w0 + n)) * 128 + (kh << 6) + (i8 << 3)) = v;
            }
        }
    }

    // ---- bias + lrelu + softmax + loss (no max pass: |z| <= ~1.5, exp safe) ----
    const int cn = (wv << 4) + lm;
    const int w  = w0 + cn;
    float s1 = 0.f;
    #pragma unroll
    for (int mt = 0; mt < 8; ++mt)
        #pragma unroll
        for (int r = 0; r < 4; ++r) {
            float z = acc[mt][r] + bcs[(mt << 4) + (q << 2) + r];
            z = z > 0.f ? z : 0.01f * z;
            float ev = __expf(z);
            acc[mt][r] = ev;
            s1 += ev;
        }
    s1 += __shfl_xor(s1, 16);
    s1 += __shfl_xor(s1, 32);
    const float inv = 1.f / s1;
    float s2 = 0.f;
    #pragma unroll
    for (int mt = 0; mt < 8; ++mt)
        #pragma unroll
        for (int r = 0; r < 4; ++r) s2 += __expf(acc[mt][r] * inv);
    s2 += __shfl_xor(s2, 16);
    s2 += __shfl_xor(s2, 32);

    int lab = 0;
    if (w < WW) {
        float g = x_gt[(size_t)h * WW + w];
        lab = (int)(g * 128.f);
        lab = lab < 0 ? 0 : (lab > 127 ? 127 : lab);
    }
    float pl = 0.f;
    #pragma unroll
    for (int mt = 0; mt < 8; ++mt)
        #pragma unroll
        for (int r = 0; r < 4; ++r)
            if (((mt << 4) + (q << 2) + r) == lab) pl = acc[mt][r] * inv;
    pl += __shfl_xor(pl, 16);
    pl += __shfl_xor(pl, 32);

    if (q == 0 && w < WW) {
        loss_out[(size_t)h * WW + w] = __logf(s2) - pl;
        labels[h * WW + w] = lab;
    }
}

// ---------------- Kernel 1 (fallback, ws-too-small path): original ----------------
__global__ __launch_bounds__(512, 4) void k1_mfma(
    const float* __restrict__ x, const float* __restrict__ x_gt,
    const float* __restrict__ Wc, const float* __restrict__ bc,
    float* __restrict__ loss_out, int* __restrict__ labels,
    ushort* __restrict__ xT, int use_xT)
{
    __shared__ ushort Wcs[128 * 128];
    __shared__ ushort Xs[128 * 64];
    __shared__ float bcs[128];

    const int h  = blockIdx.y;
    const int w0 = blockIdx.x * 128;
    const int t  = threadIdx.x;
    const int wv = t >> 6, l = t & 63;
    const int q  = l >> 4, lm = l & 15;
    const int nvalid = (WW - w0 < 128) ? (WW - w0) : 128;

    const float* Wch = Wc + (size_t)h * (CC * 128);
    #pragma unroll
    for (int it = 0; it < 8; ++it) {
        int f4 = t + (it << 9);
        float4 v = reinterpret_cast<const float4*>(Wch)[f4];
        int e = f4 << 2; int m = e >> 7, kk = e & 127;
        ushort4 u = make_ushort4(f2b(v.x), f2b(v.y), f2b(v.z), f2b(v.w));
        *reinterpret_cast<ushort4*>(&Wcs[swzA(m, kk)]) = u;
    }
    if (t < 128) bcs[t] = bc[h * CC + t];

    f32x4 acc[8];
    #pragma unroll
    for (int mt = 0; mt < 8; ++mt) acc[mt] = (f32x4){0.f, 0.f, 0.f, 0.f};

    for (int kh = 0; kh < 2; ++kh) {
        if (kh) __syncthreads();
        #pragma unroll
        for (int it = 0; it < 2; ++it) {
            int p = t + (it << 9);
            int i2 = p >> 5;
            int w = (p & 31) << 2;
            float4 v0, v1;
            if (w0 + w < WW) {
                const float* xb = x + ((size_t)(kh * 64 + i2 * 2)) * HWP + (size_t)h * WW + w0 + w;
                v0 = *reinterpret_cast<const float4*>(xb);
                v1 = *reinterpret_cast<const float4*>(xb + HWP);
            } else { v0 = make_float4(0, 0, 0, 0); v1 = v0; }
            int il = i2 << 1;
            *reinterpret_cast<ushort2*>(&Xs[swzB(w + 0, il)]) = make_ushort2(f2b(v0.x), f2b(v1.x));
            *reinterpret_cast<ushort2*>(&Xs[swzB(w + 1, il)]) = make_ushort2(f2b(v0.y), f2b(v1.y));
            *reinterpret_cast<ushort2*>(&Xs[swzB(w + 2, il)]) = make_ushort2(f2b(v0.z), f2b(v1.z));
            *reinterpret_cast<ushort2*>(&Xs[swzB(w + 3, il)]) = make_ushort2(f2b(v0.w), f2b(v1.w));
        }
        __syncthreads();

        #pragma unroll
        for (int kk = 0; kk < 2; ++kk) {
            const int kb = (kk << 5) + (q << 3);
            const int kg = (kh << 6) + kb;
            bf16x8 bfrag = *reinterpret_cast<const bf16x8*>(&Xs[swzB((wv << 4) + lm, kb)]);
            #pragma unroll
            for (int mt = 0; mt < 8; ++mt) {
                bf16x8 afrag = *reinterpret_cast<const bf16x8*>(&Wcs[swzA((mt << 4) + lm, kg)]);
                acc[mt] = __builtin_amdgcn_mfma_f32_16x16x32_bf16(afrag, bfrag, acc[mt], 0, 0, 0);
            }
        }

        if (use_xT) {
            #pragma unroll
            for (int it = 0; it < 2; ++it) {
                int g = t + (it << 9);
                int n = g >> 3, i8 = g & 7;
                if (n < nvalid) {
                    bf16x8 v = *reinterpret_cast<const bf16x8*>(&Xs[swzB(n, i8 << 3)]);
                    *reinterpret_cast<bf16x8*>(xT + ((size_t)(h * WW + w0 + n)) * 128 + (kh << 6) + (i8 << 3)) = v;
                }
            }
        }
    }

    const int cn = (wv << 4) + lm;
    const int w  = w0 + cn;
    float s1 = 0.f;
    #pragma unroll
    for (int mt = 0; mt < 8; ++mt)
        #pragma unroll
        for (int r = 0; r < 4; ++r) {
            float z = acc[mt][r] + bcs[(mt << 4) + (q << 2) + r];
            z = z > 0.f ? z : 0.01f * z;
            float ev = __expf(z);
            acc[mt][r] = ev;
            s1 += ev;
        }
    s1 += __shfl_xor(s1, 16);
    s1 += __shfl_xor(s1, 32);
    const float inv = 1.f / s1;
    float s2 = 0.f;
    #pragma unroll
    for (int mt = 0; mt < 8; ++mt)
        #pragma unroll
        for (int r = 0; r < 4; ++r) s2 += __expf(acc[mt][r] * inv);
    s2 += __shfl_xor(s2, 16);
    s2 += __shfl_xor(s2, 32);

    int lab = 0;
    if (w < WW) {
        float g = x_gt[(size_t)h * WW + w];
        lab = (int)(g * 128.f);
        lab = lab < 0 ? 0 : (lab > 127 ? 127 : lab);
    }
    float pl = 0.f;
    #pragma unroll
    for (int mt = 0; mt < 8; ++mt)
        #pragma unroll
        for (int r = 0; r < 4; ++r)
            if (((mt << 4) + (q << 2) + r) == lab) pl = acc[mt][r] * inv;
    pl += __shfl_xor(pl, 16);
    pl += __shfl_xor(pl, 32);

    if (q == 0 && w < WW) {
        loss_out[(size_t)h * WW + w] = __logf(s2) - pl;
        labels[h * WW + w] = lab;
    }
}

// ---------------- Kernel 2: MFMA expert MLP, one wave per expert (unchanged) ----------------
__global__ __launch_bounds__(256, 2) void k2_mfma(
    const float* __restrict__ x, const ushort* __restrict__ xT, int use_xT,
    const int* __restrict__ labels,
    const float* __restrict__ W1, const float* __restrict__ b1,
    const float* __restrict__ W2, const float* __restrict__ b2,
    const float* __restrict__ Wrc, const float* __restrict__ brc,
    float* __restrict__ out)
{
    __shared__ ushort wlist[WW];
    __shared__ int cnt8[G], off8[G], cur8[G];
    __shared__ ushort __align__(16) hA[4][16][40];
    __shared__ float h2s[4][16][33];
    __shared__ float wrcs[4][64];

    const int cg = blockIdx.x, h = blockIdx.y;
    const int c0 = cg * G;
    const size_t E0 = (size_t)h * CC + c0;
    const int t = threadIdx.x;
    const int wv = t >> 6, l = t & 63;
    const int lo = l & 15, g = l >> 4;

    if (t < G) { cnt8[t] = 0; cur8[t] = 0; }
    __syncthreads();

    const int* lrow = labels + h * WW;
    int myl[3];
    #pragma unroll
    for (int p = 0; p < 3; ++p) {
        int w = t + p * 256;
        myl[p] = (w < WW) ? (lrow[w] - c0) : -1;
        if (myl[p] >= 0 && myl[p] < G) atomicAdd(&cnt8[myl[p]], 1);
    }
    __syncthreads();
    if (t == 0) { int s = 0; for (int e2 = 0; e2 < G; ++e2) { off8[e2] = s; s += cnt8[e2]; } }
    __syncthreads();
    #pragma unroll
    for (int p = 0; p < 3; ++p) {
        int li = myl[p];
        if (li >= 0 && li < G) {
            int pos = off8[li] + atomicAdd(&cur8[li], 1);
            wlist[pos] = (ushort)(t + p * 256);
        }
    }
    __syncthreads();

    for (int ei = 0; ei < 2; ++ei) {
        const int li = wv + ei * 4;
        const int e_n = cnt8[li], e_off = off8[li];
        if (e_n == 0) continue;
        const size_t eg = E0 + li;
        const float* W1e = W1 + eg * 4096;
        const float* W2e = W2 + eg * 1024;

        float w1f[4][2][8];
        #pragma unroll
        for (int ks = 0; ks < 4; ++ks)
            #pragma unroll
            for (int tt = 0; tt < 2; ++tt)
                #pragma unroll
                for (int j = 0; j < 8; ++j)
                    w1f[ks][tt][j] = W1e[(ks * 32 + g * 8 + j) * 32 + tt * 16 + lo];
        float w2f[2][8];
        #pragma unroll
        for (int tt = 0; tt < 2; ++tt)
            #pragma unroll
            for (int j = 0; j < 8; ++j)
                w2f[tt][j] = W2e[(g * 8 + j) * 32 + tt * 16 + lo];
        const float b1v0 = b1[eg * 32 + lo],      b1v1 = b1[eg * 32 + 16 + lo];
        const float b2v0 = b2[eg * 32 + lo],      b2v1 = b2[eg * 32 + 16 + lo];
        const float brcv = brc[eg * 2 + (g & 1)];
        wrcs[wv][l] = Wrc[eg * 64 + l];

        bf16x8 w1b[4][2];
        #pragma unroll
        for (int ks = 0; ks < 4; ++ks)
            #pragma unroll
            for (int tt = 0; tt < 2; ++tt) {
                bf16x8 r;
                #pragma unroll
                for (int j = 0; j < 8; ++j) r[j] = (short)f2b(w1f[ks][tt][j]);
                w1b[ks][tt] = r;
            }
        bf16x8 w2b[2];
        #pragma unroll
        for (int tt = 0; tt < 2; ++tt) {
            bf16x8 r;
            #pragma unroll
            for (int j = 0; j < 8; ++j) r[j] = (short)f2b(w2f[tt][j]);
            w2b[tt] = r;
        }

        for (int pb = 0; pb < e_n; pb += 16) {
            int p_idx = pb + lo;
            int pc = (p_idx < e_n) ? p_idx : (e_n - 1);
            const int wpix = wlist[e_off + pc];

            bf16x8 af[4];
            if (use_xT) {
                const ushort* xrow = xT + (((size_t)(h * WW + wpix)) << 7);
                #pragma unroll
                for (int ks = 0; ks < 4; ++ks)
                    af[ks] = *reinterpret_cast<const bf16x8*>(xrow + ks * 32 + g * 8);
            } else {
                #pragma unroll
                for (int ks = 0; ks < 4; ++ks) {
                    bf16x8 r;
                    #pragma unroll
                    for (int j = 0; j < 8; ++j) {
                        float f = x[(size_t)(ks * 32 + g * 8 + j) * HWP + (size_t)h * WW + wpix];
                        r[j] = (short)f2b(f);
                    }
                    af[ks] = r;
                }
            }

            f32x4 a1t0 = {b1v0, b1v0, b1v0, b1v0};
            f32x4 a1t1 = {b1v1, b1v1, b1v1, b1v1};
            #pragma unroll
            for (int ks = 0; ks < 4; ++ks) {
                a1t0 = __builtin_amdgcn_mfma_f32_16x16x32_bf16(af[ks], w1b[ks][0], a1t0, 0, 0, 0);
                a1t1 = __builtin_amdgcn_mfma_f32_16x16x32_bf16(af[ks], w1b[ks][1], a1t1, 0, 0, 0);
            }
            #pragma unroll
            for (int r = 0; r < 4; ++r) {
                hA[wv][g * 4 + r][lo]      = f2b(lrelu(a1t0[r]));
                hA[wv][g * 4 + r][16 + lo] = f2b(lrelu(a1t1[r]));
            }
            bf16x8 a2 = *reinterpret_cast<const bf16x8*>(&hA[wv][lo][g * 8]);
            f32x4 a2t0 = {b2v0, b2v0, b2v0, b2v0};
            f32x4 a2t1 = {b2v1, b2v1, b2v1, b2v1};
            a2t0 = __builtin_amdgcn_mfma_f32_16x16x32_bf16(a2, w2b[0], a2t0, 0, 0, 0);
            a2t1 = __builtin_amdgcn_mfma_f32_16x16x32_bf16(a2, w2b[1], a2t1, 0, 0, 0);
            #pragma unroll
            for (int r = 0; r < 4; ++r) {
                h2s[wv][g * 4 + r][lo]      = lrelu(a2t0[r]);
                h2s[wv][g * 4 + r][16 + lo] = lrelu(a2t1[r]);
            }
            if (l < 32) {
                float a = brcv;
                #pragma unroll
                for (int i = 0; i < 32; ++i)
                    a = fmaf(h2s[wv][lo][i], wrcs[wv][i * 2 + g], a);
                a = lrelu(a);
                int p2 = pb + lo;
                if (p2 < e_n) {
                    int pix = h * WW + wlist[e_off + p2];
                    if (g == 1) out[HWP + pix] = a;
                    else        out[pix] = ((float)(c0 + li) + a) * (1.0f / 128.0f);
                }
            }
        }
    }
}

extern "C" void kernel_launch(void* const* d_in, const int* in_sizes, int n_in,
                              void* d_out, int out_size, void* d_ws, size_t ws_size,
                              hipStream_t stream)
{
    const float* x    = (const float*)d_in[0];
    const float* x_gt = (const float*)d_in[1];
    const float* Wc   = (const float*)d_in[2];
    const float* bc   = (const float*)d_in[3];
    const float* W1   = (const float*)d_in[4];
    const float* b1   = (const float*)d_in[5];
    const float* W2   = (const float*)d_in[6];
    const float* b2   = (const float*)d_in[7];
    const float* Wrc  = (const float*)d_in[8];
    const float* brc  = (const float*)d_in[9];
    float* out = (float*)d_out;

    const size_t lab_bytes = (size_t)HWP * sizeof(int);
    const size_t xT_bytes  = (size_t)HWP * 128 * sizeof(ushort);
    const size_t wcf_bytes = (size_t)HH * CC * 128 * sizeof(ushort);   // 14.68 MB

    int*    labels = (int*)d_ws;
    ushort* xT     = (ushort*)((char*)d_ws + lab_bytes);
    ushort* WcF    = (ushort*)((char*)d_ws + lab_bytes + xT_bytes);

    if (ws_size >= lab_bytes + xT_bytes + wcf_bytes) {
        hipLaunchKernelGGL(t_wcf, dim3(3584), dim3(256), 0, stream, Wc, WcF);
        hipLaunchKernelGGL(k1_fast, dim3(5, HH), dim3(512), 0, stream,
                           x, x_gt, WcF, bc, out + 2 * (size_t)HWP, labels, xT);
        hipLaunchKernelGGL(k2_mfma, dim3(CC / G, HH), dim3(256), 0, stream,
                           x, xT, 1, labels,
                           W1, b1, W2, b2, Wrc, brc, out);
    } else {
        int use_xT = (ws_size >= lab_bytes + xT_bytes) ? 1 : 0;
        hipLaunchKernelGGL(k1_mfma, dim3(5, HH), dim3(512), 0, stream,
                           x, x_gt, Wc, bc, out + 2 * (size_t)HWP, labels, xT, use_xT);
        hipLaunchKernelGGL(k2_mfma, dim3(CC / G, HH), dim3(256), 0, stream,
                           x, xT, use_xT, labels,
                           W1, b1, W2, b2, Wrc, brc, out);
    }
}

// Round 10
// 311.855 us; speedup vs baseline: 1.0081x; 1.0081x over previous
//
#include <hip/hip_runtime.h>
#include <hip/hip_bf16.h>

#define HH 448
#define WW 608
#define CC 128
#define HWP (HH*WW)
#define G 8   // experts per K2 block (4 waves x 2 rounds)

typedef __attribute__((ext_vector_type(8))) short bf16x8;
typedef __attribute__((ext_vector_type(4))) float f32x4;

__device__ __forceinline__ ushort f2b(float f) {
    __hip_bfloat16 b = __float2bfloat16(f);
    return *reinterpret_cast<ushort*>(&b);
}
__device__ __forceinline__ float b2f(ushort u) {
    union { unsigned v; float f; } x; x.v = ((unsigned)u) << 16; return x.f;
}
__device__ __forceinline__ float lrelu(float a) { return a > 0.f ? a : 0.01f * a; }

// Wcs swizzle: [m][k], k<128. group = (k>>3) ^ (m&15) -> frag reads 2-way (free)
__device__ __forceinline__ int swzA(int m, int k) {
    return m * 128 + ((((k >> 3) ^ (m & 15)) & 15) << 3) + (k & 7);
}
// Xs swizzle: [n][k], k<64. group = (k>>3) ^ (n&7) ^ ((n>>3)&7)
__device__ __forceinline__ int swzB(int n, int k) {
    return n * 64 + ((((k >> 3) ^ (n & 7) ^ ((n >> 3) & 7)) & 7) << 3) + (k & 7);
}

// ---------------- Kernel 1: MFMA classifier + in-register softmax/loss ----------------
// (round-8 structure: LDS-staged Wc; round-9-validated no-max softmax kept)
__global__ __launch_bounds__(512, 4) void k1_mfma(
    const float* __restrict__ x, const float* __restrict__ x_gt,
    const float* __restrict__ Wc, const float* __restrict__ bc,
    float* __restrict__ loss_out, int* __restrict__ labels,
    ushort* __restrict__ xT, int use_xT)
{
    __shared__ ushort Wcs[128 * 128];
    __shared__ ushort Xs[128 * 64];
    __shared__ float bcs[128];

    const int h  = blockIdx.y;
    const int w0 = blockIdx.x * 128;
    const int t  = threadIdx.x;
    const int wv = t >> 6, l = t & 63;
    const int q  = l >> 4, lm = l & 15;
    const int nvalid = (WW - w0 < 128) ? (WW - w0) : 128;

    const float* Wch = Wc + (size_t)h * (CC * 128);
    #pragma unroll
    for (int it = 0; it < 8; ++it) {
        int f4 = t + (it << 9);
        float4 v = reinterpret_cast<const float4*>(Wch)[f4];
        int e = f4 << 2; int m = e >> 7, kk = e & 127;
        ushort4 u = make_ushort4(f2b(v.x), f2b(v.y), f2b(v.z), f2b(v.w));
        *reinterpret_cast<ushort4*>(&Wcs[swzA(m, kk)]) = u;
    }
    if (t < 128) bcs[t] = bc[h * CC + t];

    f32x4 acc[8];
    #pragma unroll
    for (int mt = 0; mt < 8; ++mt) acc[mt] = (f32x4){0.f, 0.f, 0.f, 0.f};

    for (int kh = 0; kh < 2; ++kh) {
        if (kh) __syncthreads();
        #pragma unroll
        for (int it = 0; it < 2; ++it) {
            int p = t + (it << 9);
            int i2 = p >> 5;
            int w = (p & 31) << 2;
            float4 v0, v1;
            if (w0 + w < WW) {
                const float* xb = x + ((size_t)(kh * 64 + i2 * 2)) * HWP + (size_t)h * WW + w0 + w;
                v0 = *reinterpret_cast<const float4*>(xb);
                v1 = *reinterpret_cast<const float4*>(xb + HWP);
            } else { v0 = make_float4(0, 0, 0, 0); v1 = v0; }
            int il = i2 << 1;
            *reinterpret_cast<ushort2*>(&Xs[swzB(w + 0, il)]) = make_ushort2(f2b(v0.x), f2b(v1.x));
            *reinterpret_cast<ushort2*>(&Xs[swzB(w + 1, il)]) = make_ushort2(f2b(v0.y), f2b(v1.y));
            *reinterpret_cast<ushort2*>(&Xs[swzB(w + 2, il)]) = make_ushort2(f2b(v0.z), f2b(v1.z));
            *reinterpret_cast<ushort2*>(&Xs[swzB(w + 3, il)]) = make_ushort2(f2b(v0.w), f2b(v1.w));
        }
        __syncthreads();

        #pragma unroll
        for (int kk = 0; kk < 2; ++kk) {
            const int kb = (kk << 5) + (q << 3);
            const int kg = (kh << 6) + kb;
            bf16x8 bfrag = *reinterpret_cast<const bf16x8*>(&Xs[swzB((wv << 4) + lm, kb)]);
            #pragma unroll
            for (int mt = 0; mt < 8; ++mt) {
                bf16x8 afrag = *reinterpret_cast<const bf16x8*>(&Wcs[swzA((mt << 4) + lm, kg)]);
                acc[mt] = __builtin_amdgcn_mfma_f32_16x16x32_bf16(afrag, bfrag, acc[mt], 0, 0, 0);
            }
        }

        if (use_xT) {
            #pragma unroll
            for (int it = 0; it < 2; ++it) {
                int g = t + (it << 9);
                int n = g >> 3, i8 = g & 7;
                if (n < nvalid) {
                    bf16x8 v = *reinterpret_cast<const bf16x8*>(&Xs[swzB(n, i8 << 3)]);
                    *reinterpret_cast<bf16x8*>(xT + ((size_t)(h * WW + w0 + n)) * 128 + (kh << 6) + (i8 << 3)) = v;
                }
            }
        }
    }

    // ---- bias + lrelu + softmax + loss (no max pass: |z| <= ~1.5, exp safe;
    //      validated bit-identical absmax in round 9) ----
    const int cn = (wv << 4) + lm;
    const int w  = w0 + cn;
    float s1 = 0.f;
    #pragma unroll
    for (int mt = 0; mt < 8; ++mt)
        #pragma unroll
        for (int r = 0; r < 4; ++r) {
            float z = acc[mt][r] + bcs[(mt << 4) + (q << 2) + r];
            z = z > 0.f ? z : 0.01f * z;
            float ev = __expf(z);
            acc[mt][r] = ev;
            s1 += ev;
        }
    s1 += __shfl_xor(s1, 16);
    s1 += __shfl_xor(s1, 32);
    const float inv = 1.f / s1;
    float s2 = 0.f;
    #pragma unroll
    for (int mt = 0; mt < 8; ++mt)
        #pragma unroll
        for (int r = 0; r < 4; ++r) s2 += __expf(acc[mt][r] * inv);
    s2 += __shfl_xor(s2, 16);
    s2 += __shfl_xor(s2, 32);

    int lab = 0;
    if (w < WW) {
        float g = x_gt[(size_t)h * WW + w];
        lab = (int)(g * 128.f);
        lab = lab < 0 ? 0 : (lab > 127 ? 127 : lab);
    }
    float pl = 0.f;
    #pragma unroll
    for (int mt = 0; mt < 8; ++mt)
        #pragma unroll
        for (int r = 0; r < 4; ++r)
            if (((mt << 4) + (q << 2) + r) == lab) pl = acc[mt][r] * inv;
    pl += __shfl_xor(pl, 16);
    pl += __shfl_xor(pl, 32);

    if (q == 0 && w < WW) {
        loss_out[(size_t)h * WW + w] = __logf(s2) - pl;
        labels[h * WW + w] = lab;
    }
}

// ---------------- Kernel 2 (v5): MFMA expert MLP with cross-expert weight prefetch ----------------
// grid (16, 448), block 256 (4 waves). Wave wv handles experts c0+wv, c0+wv+4.
// Pipeline: loadA -> convA -> issue loadB -> computeA (B loads in flight) -> convB -> computeB.
__global__ __launch_bounds__(256, 2) void k2_mfma(
    const float* __restrict__ x, const ushort* __restrict__ xT, int use_xT,
    const int* __restrict__ labels,
    const float* __restrict__ W1, const float* __restrict__ b1,
    const float* __restrict__ W2, const float* __restrict__ b2,
    const float* __restrict__ Wrc, const float* __restrict__ brc,
    float* __restrict__ out)
{
    __shared__ ushort wlist[WW];
    __shared__ int cnt8[G], off8[G], cur8[G];
    __shared__ ushort __align__(16) hA[4][16][40];   // [wave][p][o] bf16, 80B rows
    __shared__ float h2s[4][16][33];
    __shared__ float wrcs[4][64];

    const int cg = blockIdx.x, h = blockIdx.y;
    const int c0 = cg * G;
    const size_t E0 = (size_t)h * CC + c0;
    const int t = threadIdx.x;
    const int wv = t >> 6, l = t & 63;
    const int lo = l & 15, g = l >> 4;

    if (t < G) { cnt8[t] = 0; cur8[t] = 0; }
    __syncthreads();

    // ---- label scan + per-expert compaction ----
    const int* lrow = labels + h * WW;
    int myl[3];
    #pragma unroll
    for (int p = 0; p < 3; ++p) {
        int w = t + p * 256;
        myl[p] = (w < WW) ? (lrow[w] - c0) : -1;
        if (myl[p] >= 0 && myl[p] < G) atomicAdd(&cnt8[myl[p]], 1);
    }
    __syncthreads();
    if (t == 0) { int s = 0; for (int e2 = 0; e2 < G; ++e2) { off8[e2] = s; s += cnt8[e2]; } }
    __syncthreads();
    #pragma unroll
    for (int p = 0; p < 3; ++p) {
        int li = myl[p];
        if (li >= 0 && li < G) {
            int pos = off8[li] + atomicAdd(&cur8[li], 1);
            wlist[pos] = (ushort)(t + p * 256);
        }
    }
    __syncthreads();

    const int li0 = wv, li1 = wv + 4;
    const int n0 = cnt8[li0], o0 = off8[li0];
    const int n1 = cnt8[li1], o1 = off8[li1];
    const size_t eg0 = E0 + li0, eg1 = E0 + li1;

    float f1[4][2][8], f2[2][8];                 // fp32 staging (reused A then B)
    bf16x8 w1bA[4][2], w2bA[2], w1bB[4][2], w2bB[2];

    #define LOADW(eg) do {                                                       \
        const float* W1e_ = W1 + (eg) * 4096;                                    \
        const float* W2e_ = W2 + (eg) * 1024;                                    \
        _Pragma("unroll")                                                        \
        for (int ks = 0; ks < 4; ++ks)                                           \
            _Pragma("unroll")                                                    \
            for (int tt = 0; tt < 2; ++tt)                                       \
                _Pragma("unroll")                                                \
                for (int j = 0; j < 8; ++j)                                      \
                    f1[ks][tt][j] = W1e_[(ks * 32 + g * 8 + j) * 32 + tt * 16 + lo]; \
        _Pragma("unroll")                                                        \
        for (int tt = 0; tt < 2; ++tt)                                           \
            _Pragma("unroll")                                                    \
            for (int j = 0; j < 8; ++j)                                          \
                f2[tt][j] = W2e_[(g * 8 + j) * 32 + tt * 16 + lo];               \
    } while (0)

    #define CONVW(W1B, W2B) do {                                                 \
        _Pragma("unroll")                                                        \
        for (int ks = 0; ks < 4; ++ks)                                           \
            _Pragma("unroll")                                                    \
            for (int tt = 0; tt < 2; ++tt) {                                     \
                bf16x8 r_;                                                       \
                _Pragma("unroll")                                                \
                for (int j = 0; j < 8; ++j) r_[j] = (short)f2b(f1[ks][tt][j]);   \
                W1B[ks][tt] = r_;                                                \
            }                                                                    \
        _Pragma("unroll")                                                        \
        for (int tt = 0; tt < 2; ++tt) {                                         \
            bf16x8 r_;                                                           \
            _Pragma("unroll")                                                    \
            for (int j = 0; j < 8; ++j) r_[j] = (short)f2b(f2[tt][j]);           \
            W2B[tt] = r_;                                                        \
        }                                                                        \
    } while (0)

    #define COMPUTE_EXPERT(W1B, W2B, eg, li, e_n, e_off) do {                    \
        const float b1v0 = b1[(eg) * 32 + lo], b1v1 = b1[(eg) * 32 + 16 + lo];   \
        const float b2v0 = b2[(eg) * 32 + lo], b2v1 = b2[(eg) * 32 + 16 + lo];   \
        const float brcv = brc[(eg) * 2 + (g & 1)];                              \
        wrcs[wv][l] = Wrc[(eg) * 64 + l];                                        \
        for (int pb = 0; pb < (e_n); pb += 16) {                                 \
            int p_idx = pb + lo;                                                 \
            int pc = (p_idx < (e_n)) ? p_idx : ((e_n) - 1);                      \
            const int wpix = wlist[(e_off) + pc];                                \
            bf16x8 af[4];                                                        \
            if (use_xT) {                                                        \
                const ushort* xrow = xT + (((size_t)(h * WW + wpix)) << 7);      \
                _Pragma("unroll")                                                \
                for (int ks = 0; ks < 4; ++ks)                                   \
                    af[ks] = *reinterpret_cast<const bf16x8*>(xrow + ks * 32 + g * 8); \
            } else {                                                             \
                _Pragma("unroll")                                                \
                for (int ks = 0; ks < 4; ++ks) {                                 \
                    bf16x8 r_;                                                   \
                    _Pragma("unroll")                                            \
                    for (int j = 0; j < 8; ++j) {                                \
                        float f_ = x[(size_t)(ks * 32 + g * 8 + j) * HWP + (size_t)h * WW + wpix]; \
                        r_[j] = (short)f2b(f_);                                  \
                    }                                                            \
                    af[ks] = r_;                                                 \
                }                                                                \
            }                                                                    \
            f32x4 a1t0 = {b1v0, b1v0, b1v0, b1v0};                               \
            f32x4 a1t1 = {b1v1, b1v1, b1v1, b1v1};                               \
            _Pragma("unroll")                                                    \
            for (int ks = 0; ks < 4; ++ks) {                                     \
                a1t0 = __builtin_amdgcn_mfma_f32_16x16x32_bf16(af[ks], W1B[ks][0], a1t0, 0, 0, 0); \
                a1t1 = __builtin_amdgcn_mfma_f32_16x16x32_bf16(af[ks], W1B[ks][1], a1t1, 0, 0, 0); \
            }                                                                    \
            _Pragma("unroll")                                                    \
            for (int r = 0; r < 4; ++r) {                                        \
                hA[wv][g * 4 + r][lo]      = f2b(lrelu(a1t0[r]));                \
                hA[wv][g * 4 + r][16 + lo] = f2b(lrelu(a1t1[r]));                \
            }                                                                    \
            bf16x8 a2 = *reinterpret_cast<const bf16x8*>(&hA[wv][lo][g * 8]);    \
            f32x4 a2t0 = {b2v0, b2v0, b2v0, b2v0};                               \
            f32x4 a2t1 = {b2v1, b2v1, b2v1, b2v1};                               \
            a2t0 = __builtin_amdgcn_mfma_f32_16x16x32_bf16(a2, W2B[0], a2t0, 0, 0, 0); \
            a2t1 = __builtin_amdgcn_mfma_f32_16x16x32_bf16(a2, W2B[1], a2t1, 0, 0, 0); \
            _Pragma("unroll")                                                    \
            for (int r = 0; r < 4; ++r) {                                        \
                h2s[wv][g * 4 + r][lo]      = lrelu(a2t0[r]);                    \
                h2s[wv][g * 4 + r][16 + lo] = lrelu(a2t1[r]);                    \
            }                                                                    \
            if (l < 32) {                                                        \
                float a_ = brcv;                                                 \
                _Pragma("unroll")                                                \
                for (int i = 0; i < 32; ++i)                                     \
                    a_ = fmaf(h2s[wv][lo][i], wrcs[wv][i * 2 + g], a_);          \
                a_ = lrelu(a_);                                                  \
                int p2 = pb + lo;                                                \
                if (p2 < (e_n)) {                                                \
                    int pix = h * WW + wlist[(e_off) + p2];                      \
                    if (g == 1) out[HWP + pix] = a_;                             \
                    else        out[pix] = ((float)(c0 + (li)) + a_) * (1.0f / 128.0f); \
                }                                                                \
            }                                                                    \
        }                                                                        \
    } while (0)

    // ---- software pipeline across the wave's two experts ----
    if (n0) LOADW(eg0);            // phase 1: A loads
    if (n0) CONVW(w1bA, w2bA);     // phase 2: A convert (waits on A loads)
    if (n1) LOADW(eg1);            // phase 3: B loads issued, in flight during A compute
    if (n0) COMPUTE_EXPERT(w1bA, w2bA, eg0, li0, n0, o0);   // phase 4
    if (n1) {                      // phase 5: B convert (loads have drained) + compute
        CONVW(w1bB, w2bB);
        COMPUTE_EXPERT(w1bB, w2bB, eg1, li1, n1, o1);
    }
    #undef LOADW
    #undef CONVW
    #undef COMPUTE_EXPERT
}

extern "C" void kernel_launch(void* const* d_in, const int* in_sizes, int n_in,
                              void* d_out, int out_size, void* d_ws, size_t ws_size,
                              hipStream_t stream)
{
    const float* x    = (const float*)d_in[0];
    const float* x_gt = (const float*)d_in[1];
    const float* Wc   = (const float*)d_in[2];
    const float* bc   = (const float*)d_in[3];
    const float* W1   = (const float*)d_in[4];
    const float* b1   = (const float*)d_in[5];
    const float* W2   = (const float*)d_in[6];
    const float* b2   = (const float*)d_in[7];
    const float* Wrc  = (const float*)d_in[8];
    const float* brc  = (const float*)d_in[9];
    float* out = (float*)d_out;

    const size_t lab_bytes = (size_t)HWP * sizeof(int);
    const size_t xT_bytes  = (size_t)HWP * 128 * sizeof(ushort);
    int use_xT = (ws_size >= lab_bytes + xT_bytes) ? 1 : 0;

    int*    labels = (int*)d_ws;
    ushort* xT     = (ushort*)((char*)d_ws + lab_bytes);

    hipLaunchKernelGGL(k1_mfma, dim3(5, HH), dim3(512), 0, stream,
                       x, x_gt, Wc, bc, out + 2 * (size_t)HWP, labels, xT, use_xT);
    hipLaunchKernelGGL(k2_mfma, dim3(CC / G, HH), dim3(256), 0, stream,
                       x, xT, use_xT, labels,
                       W1, b1, W2, b2, Wrc, brc, out);
}